// Round 6
// baseline (173.456 us; speedup 1.0000x reference)
//
#include <hip/hip_runtime.h>
#include <hip/hip_bf16.h>

// B=8, H=W=32 (seq=1024), C=512, heads=8, head_dim=64, groups=32
#define SEQ   1024
#define CH    512
#define NHEAD 8
#define HDIM  64
#define BATCH 8

using short8  = __attribute__((ext_vector_type(8))) short;
using short4v = __attribute__((ext_vector_type(4))) short;
using floatx4 = __attribute__((ext_vector_type(4))) float;

__device__ inline unsigned short f2bf(float f) {
  __hip_bfloat16 h = __float2bfloat16(f);
  return __builtin_bit_cast(unsigned short, h);
}

// async 16B global->LDS DMA (lane-linear LDS dest required)
__device__ inline void load_lds16(const void* g, void* l) {
  __builtin_amdgcn_global_load_lds(
      (const __attribute__((address_space(1))) unsigned int*)g,
      (__attribute__((address_space(3))) unsigned int*)l, 16, 0, 0);
}

// ---------------------------------------------------------------------------
// K1: fused prep. blocks 0..767: wqkv transpose->bf16; 768..1023: wout
// transpose; 1024..1279: groupnorm (register-resident single read of x).
// ---------------------------------------------------------------------------
__global__ __launch_bounds__(256) void prep_kernel(
    const float* __restrict__ wqkv, const float* __restrict__ wout,
    const float* __restrict__ x, const float* __restrict__ gsc,
    const float* __restrict__ gbs,
    unsigned short* __restrict__ wqkvt, unsigned short* __restrict__ woutt,
    unsigned short* __restrict__ xn) {
  __shared__ float SH[32 * 33 + 8];
  const int blk = blockIdx.x, tid = threadIdx.x;

  if (blk < 1024) {
    const float* src; unsigned short* dst; int C, bx, by;
    if (blk < 768) { src = wqkv; dst = wqkvt; C = 1536; bx = blk % 48; by = blk / 48; }
    else { int t = blk - 768; src = wout; dst = woutt; C = 512; bx = t & 15; by = t >> 4; }
    float (*T)[33] = (float(*)[33])SH;
    int tx = tid & 31, ty = tid >> 5;
    for (int j = 0; j < 4; ++j)
      T[ty + j * 8][tx] = src[(size_t)(by * 32 + ty + j * 8) * C + bx * 32 + tx];
    __syncthreads();
    for (int j = 0; j < 4; ++j)
      dst[(size_t)(bx * 32 + ty + j * 8) * 512 + by * 32 + tx] = f2bf(T[tx][ty + j * 8]);
    return;
  }

  int bg = blk - 1024;
  int b = bg >> 5, g = bg & 31;
  const size_t base = (size_t)b * SEQ * CH + g * 16;

  // single read: 16 float4 per thread held in registers
  float4 v[16];
  float s = 0.f, sq = 0.f;
  for (int i = 0; i < 16; ++i) {
    int c = i * 256 + tid;
    int r = c >> 2, c4 = (c & 3) * 4;
    v[i] = *(const float4*)(x + base + (size_t)r * CH + c4);
    s  += v[i].x + v[i].y + v[i].z + v[i].w;
    sq += v[i].x * v[i].x + v[i].y * v[i].y + v[i].z * v[i].z + v[i].w * v[i].w;
  }
  for (int off = 1; off < 64; off <<= 1) {
    s  += __shfl_xor(s, off);
    sq += __shfl_xor(sq, off);
  }
  float* ls = SH + 1056;
  float* lq = SH + 1060;
  int wid = tid >> 6, lane = tid & 63;
  if (lane == 0) { ls[wid] = s; lq[wid] = sq; }
  __syncthreads();
  float ts = ls[0] + ls[1] + ls[2] + ls[3];
  float tq = lq[0] + lq[1] + lq[2] + lq[3];
  const float inv_n = 1.0f / 16384.0f;
  float mean = ts * inv_n;
  float var  = tq * inv_n - mean * mean;
  float rstd = rsqrtf(var + 1e-6f);

  int c4 = (tid & 3) * 4;
  float4 sc = *(const float4*)(gsc + g * 16 + c4);
  float4 bs = *(const float4*)(gbs + g * 16 + c4);
  for (int i = 0; i < 16; ++i) {
    int c = i * 256 + tid;
    int r = c >> 2;
    ushort4 o;
    o.x = f2bf((v[i].x - mean) * rstd * sc.x + bs.x);
    o.y = f2bf((v[i].y - mean) * rstd * sc.y + bs.y);
    o.z = f2bf((v[i].z - mean) * rstd * sc.z + bs.z);
    o.w = f2bf((v[i].w - mean) * rstd * sc.w + bs.w);
    *(ushort4*)(xn + (size_t)(b * SEQ + r) * CH + g * 16 + c4) = o;
  }
}

// ---------------------------------------------------------------------------
// K2/K4: GEMM C = A(MxK) * Bt(NxK)^T, bf16 in, fp32 acc, MTILE x 128 tile.
// BK=64, global_load_lds staging, XOR-swizzled LDS. Epilogues via LDS ->
// 16B global stores.
// EPI 0 (MTILE=128, QKV): +bias; q scaled (1/64)*log2e; q/k -> (h,s,d);
//                         v -> transposed vt (h,d,s).
// EPI 1 (MTILE=64, out):  +bias +residual, fp32 out.
// ---------------------------------------------------------------------------
template <int EPI, int MTILE>
__global__ __launch_bounds__(256) void gemm_bt_kernel(
    const unsigned short* __restrict__ A, const unsigned short* __restrict__ Bt,
    int K, int N,
    const float* __restrict__ bias, const float* __restrict__ resid,
    float* __restrict__ outf,
    unsigned short* __restrict__ qb, unsigned short* __restrict__ kb,
    unsigned short* __restrict__ vtb) {
  constexpr int SMSZ = (MTILE == 128) ? 17408 : 16896;
  constexpr int NI   = (MTILE == 128) ? 4 : 2;
  __shared__ alignas(16) unsigned short SM[SMSZ];
  unsigned short* LA = SM;                 // MTILE x 64, swizzled
  unsigned short* LB = SM + MTILE * 64;    // 128 x 64, swizzled

  const int tid = threadIdx.x;
  const int wid = tid >> 6, lane = tid & 63;
  const int quad = lane >> 4, m16 = lane & 15;
  const int sw = m16 & 7;
  const int wm = (MTILE == 128) ? (wid & 1) * 64 : 0;
  const int wn = (MTILE == 128) ? (wid >> 1) * 64 : wid * 32;
  const int m0 = blockIdx.y * MTILE, n0 = blockIdx.x * 128;

  floatx4 acc[4][NI];
  for (int i = 0; i < 4; ++i)
    for (int j = 0; j < NI; ++j) acc[i][j] = 0.f;

  for (int k0 = 0; k0 < K; k0 += 64) {
    for (int i = 0; i < MTILE / 32; ++i) {
      int c = i * 256 + tid;
      int r = c >> 3, kc = c & 7;
      load_lds16(A + (size_t)(m0 + r) * K + k0 + ((kc ^ (r & 7)) << 3), &LA[c << 3]);
    }
    for (int i = 0; i < 4; ++i) {
      int c = i * 256 + tid;
      int r = c >> 3, kc = c & 7;
      load_lds16(Bt + (size_t)(n0 + r) * K + k0 + ((kc ^ (r & 7)) << 3), &LB[c << 3]);
    }
    __syncthreads();
    for (int kq = 0; kq < 2; ++kq) {
      int csw = (((kq << 2) + quad) ^ sw) << 3;
      short8 af[4], bf[NI];
      for (int mi = 0; mi < 4; ++mi)
        af[mi] = *(const short8*)&LA[(wm + mi * 16 + m16) * 64 + csw];
      for (int ni = 0; ni < NI; ++ni)
        bf[ni] = *(const short8*)&LB[(wn + ni * 16 + m16) * 64 + csw];
      for (int mi = 0; mi < 4; ++mi)
        for (int ni = 0; ni < NI; ++ni)
          acc[mi][ni] = __builtin_amdgcn_mfma_f32_16x16x32_bf16(af[mi], bf[ni], acc[mi][ni], 0, 0, 0);
    }
    __syncthreads();
  }

  // C/D layout: row = quad*4+reg, col = lane&15
  const int b = m0 >> 10;
  if (EPI == 0) {
    const int part = blockIdx.x >> 2;        // 0=q 1=k 2=v (block-uniform)
    if (part < 2) {
      const float qscale = (part == 0) ? 0.0225421381f : 1.0f;  // (1/64)*log2e
      unsigned short* dst = (part == 0) ? qb : kb;
      for (int mi = 0; mi < 4; ++mi)
        for (int ni = 0; ni < 4; ++ni) {
          int ln = wn + ni * 16 + m16;
          float bb = bias[n0 + ln];
          for (int reg = 0; reg < 4; ++reg)
            SM[(wm + mi * 16 + quad * 4 + reg) * 136 + ln] =
                f2bf((acc[mi][ni][reg] + bb) * qscale);
        }
      __syncthreads();
      const int colb = n0 & 511;
      for (int j = 0; j < 8; ++j) {
        int c = j * 256 + tid;               // 2048 16B chunks
        int m = c >> 4, n8 = (c & 15) * 8;
        int h = (colb + n8) >> 6, d = n8 & 63;
        int sp = (m0 & 1023) + m;
        int4 v = *(const int4*)&SM[m * 136 + n8];
        *(int4*)(dst + (((size_t)(b * NHEAD + h)) * SEQ + sp) * HDIM + d) = v;
      }
    } else {
      for (int mi = 0; mi < 4; ++mi)
        for (int ni = 0; ni < 4; ++ni) {
          int ln = wn + ni * 16 + m16;
          float bb = bias[n0 + ln];
          for (int reg = 0; reg < 4; ++reg) {
            int lm = wm + mi * 16 + quad * 4 + reg;
            SM[ln * 136 + lm] = f2bf(acc[mi][ni][reg] + bb);
          }
        }
      __syncthreads();
      int hbase = (n0 - 1024) >> 6;
      for (int j = 0; j < 8; ++j) {
        int c = j * 256 + tid;
        int ld = c >> 4, sp8 = (c & 15) * 8;
        int h = hbase + (ld >> 6), d = ld & 63;
        int4 v = *(const int4*)&SM[ld * 136 + sp8];
        *(int4*)(vtb + ((size_t)(b * NHEAD + h) * HDIM + d) * SEQ + (m0 & 1023) + sp8) = v;
      }
    }
  } else {
    float* SMf = (float*)SM;                 // 64 x 132 fp32
    for (int mi = 0; mi < 4; ++mi)
      for (int ni = 0; ni < NI; ++ni) {
        int ln = wn + ni * 16 + m16;
        float bb = bias[n0 + ln];
        for (int reg = 0; reg < 4; ++reg)
          SMf[(mi * 16 + quad * 4 + reg) * 132 + ln] = acc[mi][ni][reg] + bb;
      }
    __syncthreads();
    for (int j = 0; j < 8; ++j) {
      int c = j * 256 + tid;                 // 2048 float4 chunks
      int m = c >> 5, n4 = (c & 31) * 4;
      size_t idx = (size_t)(m0 + m) * N + n0 + n4;
      float4 v = *(const float4*)&SMf[m * 132 + n4];
      float4 rr = *(const float4*)&resid[idx];
      v.x += rr.x; v.y += rr.y; v.z += rr.z; v.w += rr.w;
      *(float4*)&outf[idx] = v;
    }
  }
}

// ---------------------------------------------------------------------------
// K3: flash attention, St = K*Q^T, no running max.  256 thr, 4 waves x
// 32 q-rows (2 q-frags share every K/V fragment read -> half the LDS traffic
// of 16-row waves).  Single-buffered 32KB LDS; VGPR capped 128 via
// __launch_bounds__(256,4) -> 4 blocks/CU = 16 waves/CU.
// (r4 failed this layout at 132 VGPR + 64KB dbuf = 8 waves/CU; both fixed.)
// ---------------------------------------------------------------------------
__global__ __launch_bounds__(256, 4) void attn_kernel(
    const unsigned short* __restrict__ qb, const unsigned short* __restrict__ kb,
    const unsigned short* __restrict__ vtb, unsigned short* __restrict__ ao) {
  const int qt = blockIdx.x, head = blockIdx.y;
  const int b = head >> 3, h = head & 7;
  const int tid = threadIdx.x;
  const int wid = tid >> 6, lane = tid & 63;
  const int quad = lane >> 4, m16 = lane & 15;
  const int sw = m16 & 7;

  __shared__ alignas(16) unsigned short sK[8192];   // 128x64, swizzled
  __shared__ alignas(16) unsigned short sV[8192];   // Vt 64x128, swizzled

  const unsigned short* kbase = kb  + (size_t)head * SEQ * HDIM;
  const unsigned short* vbase = vtb + (size_t)head * HDIM * SEQ;

  // Q fragments: 32 q-rows per wave (2 m-frags), pre-scaled (1/64)*log2e
  short8 aq[2][2];
  for (int mi = 0; mi < 2; ++mi) {
    const size_t qrow = (size_t)head * SEQ + qt * 128 + wid * 32 + mi * 16 + m16;
    aq[mi][0] = *(const short8*)(qb + qrow * HDIM + quad * 8);
    aq[mi][1] = *(const short8*)(qb + qrow * HDIM + 32 + quad * 8);
  }

  float lacc[2] = {0.f, 0.f};
  floatx4 o[2][4];
  for (int mi = 0; mi < 2; ++mi)
    for (int df = 0; df < 4; ++df) o[mi][df] = 0.f;

  for (int kt = 0; kt < 8; ++kt) {
    // stage K tile (128x64) and Vt tile (64x128)
    for (int i = 0; i < 4; ++i) {
      int c = i * 256 + tid;
      int r = c >> 3, kc = c & 7;
      load_lds16(kbase + (kt * 128 + r) * HDIM + ((kc ^ (r & 7)) << 3), &sK[c << 3]);
    }
    for (int i = 0; i < 4; ++i) {
      int c = i * 256 + tid;
      int d = c >> 4, kc = c & 15;
      load_lds16(vbase + d * SEQ + kt * 128 + ((kc ^ (d & 7)) << 3), &sV[c << 3]);
    }
    __syncthreads();

    // St = K*Q^T per s-fragment; exp2 + pack immediately (no st array live)
    short4v pf[2][8];
    for (int sf = 0; sf < 8; ++sf) {
      const int rb = (sf * 16 + m16) * 64;
      short8 k0 = *(const short8*)&sK[rb + ((quad ^ sw) << 3)];
      short8 k1 = *(const short8*)&sK[rb + (((4 + quad) ^ sw) << 3)];
      for (int mi = 0; mi < 2; ++mi) {
        floatx4 s = 0.f;
        s = __builtin_amdgcn_mfma_f32_16x16x32_bf16(k0, aq[mi][0], s, 0, 0, 0);
        s = __builtin_amdgcn_mfma_f32_16x16x32_bf16(k1, aq[mi][1], s, 0, 0, 0);
        for (int r = 0; r < 4; ++r) {
          float p = exp2f(s[r]);
          lacc[mi] += p;
          pf[mi][sf][r] = (short)f2bf(p);
        }
      }
    }

    // O += P*V (each V fragment feeds both q-frags)
    for (int kc = 0; kc < 8; ++kc) {
      int slot = ((((kc << 1) + (quad >> 1)) ^ sw) << 3) + ((quad & 1) << 2);
      for (int df = 0; df < 4; ++df) {
        short4v bv = *(const short4v*)&sV[(df * 16 + m16) * 128 + slot];
        o[0][df] = __builtin_amdgcn_mfma_f32_16x16x16bf16_1k(pf[0][kc], bv, o[0][df], 0, 0, 0);
        o[1][df] = __builtin_amdgcn_mfma_f32_16x16x16bf16_1k(pf[1][kc], bv, o[1][df], 0, 0, 0);
      }
    }
    __syncthreads();
  }

  // reduce denominators across quads (per q-col m16), normalize, write
  for (int mi = 0; mi < 2; ++mi) {
    lacc[mi] += __shfl_xor(lacc[mi], 16);
    lacc[mi] += __shfl_xor(lacc[mi], 32);
    lacc[mi] = 1.0f / lacc[mi];
  }
  for (int mi = 0; mi < 2; ++mi) {
    float l0 = __shfl(lacc[mi], quad * 4 + 0);
    float l1 = __shfl(lacc[mi], quad * 4 + 1);
    float l2 = __shfl(lacc[mi], quad * 4 + 2);
    float l3 = __shfl(lacc[mi], quad * 4 + 3);
    int qg = qt * 128 + wid * 32 + mi * 16 + quad * 4;
    for (int df = 0; df < 4; ++df) {
      int col = h * HDIM + df * 16 + m16;
      size_t base = (size_t)(b * SEQ + qg) * CH + col;
      ao[base + 0 * CH] = f2bf(o[mi][df][0] * l0);
      ao[base + 1 * CH] = f2bf(o[mi][df][1] * l1);
      ao[base + 2 * CH] = f2bf(o[mi][df][2] * l2);
      ao[base + 3 * CH] = f2bf(o[mi][df][3] * l3);
    }
  }
}

// ---------------------------------------------------------------------------
extern "C" void kernel_launch(void* const* d_in, const int* in_sizes, int n_in,
                              void* d_out, int out_size, void* d_ws, size_t ws_size,
                              hipStream_t stream) {
  const float* x    = (const float*)d_in[0];
  const float* gsc  = (const float*)d_in[1];
  const float* gbs  = (const float*)d_in[2];
  const float* wqkv = (const float*)d_in[3];
  const float* bqkv = (const float*)d_in[4];
  const float* wout = (const float*)d_in[5];
  const float* bout = (const float*)d_in[6];
  float* out = (float*)d_out;

  char* ws = (char*)d_ws;
  unsigned short* xn    = (unsigned short*)(ws);                 // 8 MB (8192x512)
  unsigned short* wqkvt = (unsigned short*)(ws + 8388608);       // 1.5 MB (1536x512)
  unsigned short* woutt = (unsigned short*)(ws + 9961472);       // 0.5 MB (512x512)
  unsigned short* qb    = (unsigned short*)(ws + 10485760);      // 8 MB (64,1024,64)
  unsigned short* kb    = (unsigned short*)(ws + 18874368);      // 8 MB (64,1024,64)
  unsigned short* vtb   = (unsigned short*)(ws + 27262976);      // 8 MB (64,64,1024)
  unsigned short* ao    = (unsigned short*)(ws + 35651584);      // 8 MB (8192x512)

  prep_kernel<<<1280, 256, 0, stream>>>(wqkv, wout, x, gsc, gbs, wqkvt, woutt, xn);
  gemm_bt_kernel<0, 128><<<dim3(12, 64), 256, 0, stream>>>(
      xn, wqkvt, 512, 1536, bqkv, nullptr, nullptr, qb, kb, vtb);
  attn_kernel<<<dim3(8, 64), 256, 0, stream>>>(qb, kb, vtb, ao);
  gemm_bt_kernel<1, 64><<<dim3(4, 128), 256, 0, stream>>>(
      ao, woutt, 512, 512, bout, x, out, nullptr, nullptr, nullptr);
}

// Round 7
// 172.474 us; speedup vs baseline: 1.0057x; 1.0057x over previous
//
#include <hip/hip_runtime.h>
#include <hip/hip_bf16.h>

// B=8, H=W=32 (seq=1024), C=512, heads=8, head_dim=64, groups=32
#define SEQ   1024
#define CH    512
#define NHEAD 8
#define HDIM  64
#define BATCH 8

using short8  = __attribute__((ext_vector_type(8))) short;
using short4v = __attribute__((ext_vector_type(4))) short;
using floatx4 = __attribute__((ext_vector_type(4))) float;

__device__ inline unsigned short f2bf(float f) {
  __hip_bfloat16 h = __float2bfloat16(f);
  return __builtin_bit_cast(unsigned short, h);
}

// async 16B global->LDS DMA (lane-linear LDS dest required)
__device__ inline void load_lds16(const void* g, void* l) {
  __builtin_amdgcn_global_load_lds(
      (const __attribute__((address_space(1))) unsigned int*)g,
      (__attribute__((address_space(3))) unsigned int*)l, 16, 0, 0);
}

// ---------------------------------------------------------------------------
// K1: fused prep. blocks 0..767: wqkv transpose->bf16; 768..1023: wout
// transpose; 1024..1279: groupnorm (register-resident single read of x).
// ---------------------------------------------------------------------------
__global__ __launch_bounds__(256) void prep_kernel(
    const float* __restrict__ wqkv, const float* __restrict__ wout,
    const float* __restrict__ x, const float* __restrict__ gsc,
    const float* __restrict__ gbs,
    unsigned short* __restrict__ wqkvt, unsigned short* __restrict__ woutt,
    unsigned short* __restrict__ xn) {
  __shared__ float SH[32 * 33 + 8];
  const int blk = blockIdx.x, tid = threadIdx.x;

  if (blk < 1024) {
    const float* src; unsigned short* dst; int C, bx, by;
    if (blk < 768) { src = wqkv; dst = wqkvt; C = 1536; bx = blk % 48; by = blk / 48; }
    else { int t = blk - 768; src = wout; dst = woutt; C = 512; bx = t & 15; by = t >> 4; }
    float (*T)[33] = (float(*)[33])SH;
    int tx = tid & 31, ty = tid >> 5;
    for (int j = 0; j < 4; ++j)
      T[ty + j * 8][tx] = src[(size_t)(by * 32 + ty + j * 8) * C + bx * 32 + tx];
    __syncthreads();
    for (int j = 0; j < 4; ++j)
      dst[(size_t)(bx * 32 + ty + j * 8) * 512 + by * 32 + tx] = f2bf(T[tx][ty + j * 8]);
    return;
  }

  int bg = blk - 1024;
  int b = bg >> 5, g = bg & 31;
  const size_t base = (size_t)b * SEQ * CH + g * 16;

  // single read: 16 float4 per thread held in registers
  float4 v[16];
  float s = 0.f, sq = 0.f;
  for (int i = 0; i < 16; ++i) {
    int c = i * 256 + tid;
    int r = c >> 2, c4 = (c & 3) * 4;
    v[i] = *(const float4*)(x + base + (size_t)r * CH + c4);
    s  += v[i].x + v[i].y + v[i].z + v[i].w;
    sq += v[i].x * v[i].x + v[i].y * v[i].y + v[i].z * v[i].z + v[i].w * v[i].w;
  }
  for (int off = 1; off < 64; off <<= 1) {
    s  += __shfl_xor(s, off);
    sq += __shfl_xor(sq, off);
  }
  float* ls = SH + 1056;
  float* lq = SH + 1060;
  int wid = tid >> 6, lane = tid & 63;
  if (lane == 0) { ls[wid] = s; lq[wid] = sq; }
  __syncthreads();
  float ts = ls[0] + ls[1] + ls[2] + ls[3];
  float tq = lq[0] + lq[1] + lq[2] + lq[3];
  const float inv_n = 1.0f / 16384.0f;
  float mean = ts * inv_n;
  float var  = tq * inv_n - mean * mean;
  float rstd = rsqrtf(var + 1e-6f);

  int c4 = (tid & 3) * 4;
  float4 sc = *(const float4*)(gsc + g * 16 + c4);
  float4 bs = *(const float4*)(gbs + g * 16 + c4);
  for (int i = 0; i < 16; ++i) {
    int c = i * 256 + tid;
    int r = c >> 2;
    ushort4 o;
    o.x = f2bf((v[i].x - mean) * rstd * sc.x + bs.x);
    o.y = f2bf((v[i].y - mean) * rstd * sc.y + bs.y);
    o.z = f2bf((v[i].z - mean) * rstd * sc.z + bs.z);
    o.w = f2bf((v[i].w - mean) * rstd * sc.w + bs.w);
    *(ushort4*)(xn + (size_t)(b * SEQ + r) * CH + g * 16 + c4) = o;
  }
}

// ---------------------------------------------------------------------------
// K2/K4: GEMM C = A(MxK) * Bt(NxK)^T, bf16 in, fp32 acc, MTILE x 128 tile.
// BK=64, global_load_lds staging, XOR-swizzled LDS. Epilogues via LDS ->
// 16B global stores.
// EPI 0 (MTILE=128, QKV): +bias; q scaled (1/64)*log2e; q/k -> (h,s,d);
//                         v -> transposed vt (h,d,s).
// EPI 1 (MTILE=64, out):  +bias +residual, fp32 out.
// ---------------------------------------------------------------------------
template <int EPI, int MTILE>
__global__ __launch_bounds__(256) void gemm_bt_kernel(
    const unsigned short* __restrict__ A, const unsigned short* __restrict__ Bt,
    int K, int N,
    const float* __restrict__ bias, const float* __restrict__ resid,
    float* __restrict__ outf,
    unsigned short* __restrict__ qb, unsigned short* __restrict__ kb,
    unsigned short* __restrict__ vtb) {
  constexpr int SMSZ = (MTILE == 128) ? 17408 : 16896;
  constexpr int NI   = (MTILE == 128) ? 4 : 2;
  __shared__ alignas(16) unsigned short SM[SMSZ];
  unsigned short* LA = SM;                 // MTILE x 64, swizzled
  unsigned short* LB = SM + MTILE * 64;    // 128 x 64, swizzled

  const int tid = threadIdx.x;
  const int wid = tid >> 6, lane = tid & 63;
  const int quad = lane >> 4, m16 = lane & 15;
  const int sw = m16 & 7;
  const int wm = (MTILE == 128) ? (wid & 1) * 64 : 0;
  const int wn = (MTILE == 128) ? (wid >> 1) * 64 : wid * 32;
  const int m0 = blockIdx.y * MTILE, n0 = blockIdx.x * 128;

  floatx4 acc[4][NI];
  for (int i = 0; i < 4; ++i)
    for (int j = 0; j < NI; ++j) acc[i][j] = 0.f;

  for (int k0 = 0; k0 < K; k0 += 64) {
    for (int i = 0; i < MTILE / 32; ++i) {
      int c = i * 256 + tid;
      int r = c >> 3, kc = c & 7;
      load_lds16(A + (size_t)(m0 + r) * K + k0 + ((kc ^ (r & 7)) << 3), &LA[c << 3]);
    }
    for (int i = 0; i < 4; ++i) {
      int c = i * 256 + tid;
      int r = c >> 3, kc = c & 7;
      load_lds16(Bt + (size_t)(n0 + r) * K + k0 + ((kc ^ (r & 7)) << 3), &LB[c << 3]);
    }
    __syncthreads();
    for (int kq = 0; kq < 2; ++kq) {
      int csw = (((kq << 2) + quad) ^ sw) << 3;
      short8 af[4], bf[NI];
      for (int mi = 0; mi < 4; ++mi)
        af[mi] = *(const short8*)&LA[(wm + mi * 16 + m16) * 64 + csw];
      for (int ni = 0; ni < NI; ++ni)
        bf[ni] = *(const short8*)&LB[(wn + ni * 16 + m16) * 64 + csw];
      for (int mi = 0; mi < 4; ++mi)
        for (int ni = 0; ni < NI; ++ni)
          acc[mi][ni] = __builtin_amdgcn_mfma_f32_16x16x32_bf16(af[mi], bf[ni], acc[mi][ni], 0, 0, 0);
    }
    __syncthreads();
  }

  // C/D layout: row = quad*4+reg, col = lane&15
  const int b = m0 >> 10;
  if (EPI == 0) {
    const int part = blockIdx.x >> 2;        // 0=q 1=k 2=v (block-uniform)
    if (part < 2) {
      const float qscale = (part == 0) ? 0.0225421381f : 1.0f;  // (1/64)*log2e
      unsigned short* dst = (part == 0) ? qb : kb;
      for (int mi = 0; mi < 4; ++mi)
        for (int ni = 0; ni < 4; ++ni) {
          int ln = wn + ni * 16 + m16;
          float bb = bias[n0 + ln];
          for (int reg = 0; reg < 4; ++reg)
            SM[(wm + mi * 16 + quad * 4 + reg) * 136 + ln] =
                f2bf((acc[mi][ni][reg] + bb) * qscale);
        }
      __syncthreads();
      const int colb = n0 & 511;
      for (int j = 0; j < 8; ++j) {
        int c = j * 256 + tid;               // 2048 16B chunks
        int m = c >> 4, n8 = (c & 15) * 8;
        int h = (colb + n8) >> 6, d = n8 & 63;
        int sp = (m0 & 1023) + m;
        int4 v = *(const int4*)&SM[m * 136 + n8];
        *(int4*)(dst + (((size_t)(b * NHEAD + h)) * SEQ + sp) * HDIM + d) = v;
      }
    } else {
      for (int mi = 0; mi < 4; ++mi)
        for (int ni = 0; ni < 4; ++ni) {
          int ln = wn + ni * 16 + m16;
          float bb = bias[n0 + ln];
          for (int reg = 0; reg < 4; ++reg) {
            int lm = wm + mi * 16 + quad * 4 + reg;
            SM[ln * 136 + lm] = f2bf(acc[mi][ni][reg] + bb);
          }
        }
      __syncthreads();
      int hbase = (n0 - 1024) >> 6;
      for (int j = 0; j < 8; ++j) {
        int c = j * 256 + tid;
        int ld = c >> 4, sp8 = (c & 15) * 8;
        int h = hbase + (ld >> 6), d = ld & 63;
        int4 v = *(const int4*)&SM[ld * 136 + sp8];
        *(int4*)(vtb + ((size_t)(b * NHEAD + h) * HDIM + d) * SEQ + (m0 & 1023) + sp8) = v;
      }
    }
  } else {
    float* SMf = (float*)SM;                 // 64 x 132 fp32
    for (int mi = 0; mi < 4; ++mi)
      for (int ni = 0; ni < NI; ++ni) {
        int ln = wn + ni * 16 + m16;
        float bb = bias[n0 + ln];
        for (int reg = 0; reg < 4; ++reg)
          SMf[(mi * 16 + quad * 4 + reg) * 132 + ln] = acc[mi][ni][reg] + bb;
      }
    __syncthreads();
    for (int j = 0; j < 8; ++j) {
      int c = j * 256 + tid;                 // 2048 float4 chunks
      int m = c >> 5, n4 = (c & 31) * 4;
      size_t idx = (size_t)(m0 + m) * N + n0 + n4;
      float4 v = *(const float4*)&SMf[m * 132 + n4];
      float4 rr = *(const float4*)&resid[idx];
      v.x += rr.x; v.y += rr.y; v.z += rr.z; v.w += rr.w;
      *(float4*)&outf[idx] = v;
    }
  }
}

// ---------------------------------------------------------------------------
// K3: flash attention, St = K*Q^T, no running max, IN-BLOCK SPLIT-K.
// 512 thr / 8 waves (grid 512 -> 2 blocks/CU -> 16 waves/CU, the measured
// occupancy sweet spot).  Waves 0-3 process kt 0-3, waves 4-7 process kt 4-7;
// each wave owns 32 q-rows so every K/V fragment read feeds 2 q-fragments
// (half the LDS traffic of r5).  Max-free softmax => partials combine by
// simple addition through LDS at the end.
// ---------------------------------------------------------------------------
__global__ __launch_bounds__(512) void attn_kernel(
    const unsigned short* __restrict__ qb, const unsigned short* __restrict__ kb,
    const unsigned short* __restrict__ vtb, unsigned short* __restrict__ ao) {
  const int qt = blockIdx.x, head = blockIdx.y;
  const int b = head >> 3, h = head & 7;
  const int tid = threadIdx.x;
  const int wid = tid >> 6, lane = tid & 63;
  const int quad = lane >> 4, m16 = lane & 15;
  const int sw = m16 & 7;
  const int p = wid & 3;          // q-row group (32 rows each)
  const int g = wid >> 2;         // kt group: 0 -> kt 0..3, 1 -> kt 4..7

  __shared__ alignas(16) unsigned short sK[2][8192];   // per-group K tile 128x64
  __shared__ alignas(16) unsigned short sV[2][8192];   // per-group Vt tile 64x128

  const unsigned short* kbase = kb  + (size_t)head * SEQ * HDIM;
  const unsigned short* vbase = vtb + (size_t)head * HDIM * SEQ;

  // Q fragments: 32 q-rows per wave (2 m-frags), pre-scaled (1/64)*log2e
  short8 aq[2][2];
  for (int mi = 0; mi < 2; ++mi) {
    const size_t qrow = (size_t)head * SEQ + qt * 128 + p * 32 + mi * 16 + m16;
    aq[mi][0] = *(const short8*)(qb + qrow * HDIM + quad * 8);
    aq[mi][1] = *(const short8*)(qb + qrow * HDIM + 32 + quad * 8);
  }

  float lacc[2] = {0.f, 0.f};
  floatx4 o[2][4];
  for (int mi = 0; mi < 2; ++mi)
    for (int df = 0; df < 4; ++df) o[mi][df] = 0.f;

  for (int it = 0; it < 4; ++it) {
    // stage BOTH groups' tile sets: tile 0 = kt it, tile 1 = kt it+4
    for (int i = 0; i < 8; ++i) {
      int c = i * 512 + tid;            // 4096 16B chunks
      int t = c >> 11, cc = c & 2047;
      int kt = it + t * 4;
      if (cc < 1024) {                  // K chunk: 128 rows x 8 chunks
        int r = cc >> 3, kc = cc & 7;
        load_lds16(kbase + (kt * 128 + r) * HDIM + ((kc ^ (r & 7)) << 3),
                   &sK[t][cc << 3]);
      } else {                          // V chunk: 64 rows x 16 chunks
        int cv = cc - 1024;
        int d = cv >> 4, kc = cv & 15;
        load_lds16(vbase + d * SEQ + kt * 128 + ((kc ^ (d & 7)) << 3),
                   &sV[t][cv << 3]);
      }
    }
    __syncthreads();

    // St = K*Q^T per s-fragment; exp2 + pack immediately
    short4v pf[2][8];
    for (int sf = 0; sf < 8; ++sf) {
      const int rb = (sf * 16 + m16) * 64;
      short8 k0 = *(const short8*)&sK[g][rb + ((quad ^ sw) << 3)];
      short8 k1 = *(const short8*)&sK[g][rb + (((4 + quad) ^ sw) << 3)];
      for (int mi = 0; mi < 2; ++mi) {
        floatx4 s = 0.f;
        s = __builtin_amdgcn_mfma_f32_16x16x32_bf16(k0, aq[mi][0], s, 0, 0, 0);
        s = __builtin_amdgcn_mfma_f32_16x16x32_bf16(k1, aq[mi][1], s, 0, 0, 0);
        for (int r = 0; r < 4; ++r) {
          float pe = exp2f(s[r]);
          lacc[mi] += pe;
          pf[mi][sf][r] = (short)f2bf(pe);
        }
      }
    }

    // O += P*V (each V fragment feeds both q-frags)
    for (int kc = 0; kc < 8; ++kc) {
      int slot = ((((kc << 1) + (quad >> 1)) ^ sw) << 3) + ((quad & 1) << 2);
      for (int df = 0; df < 4; ++df) {
        short4v bv = *(const short4v*)&sV[g][(df * 16 + m16) * 128 + slot];
        o[0][df] = __builtin_amdgcn_mfma_f32_16x16x16bf16_1k(pf[0][kc], bv, o[0][df], 0, 0, 0);
        o[1][df] = __builtin_amdgcn_mfma_f32_16x16x16bf16_1k(pf[1][kc], bv, o[1][df], 0, 0, 0);
      }
    }
    __syncthreads();
  }

  // combine group B partials into group A via LDS (exact: max-free softmax)
  float* FB = (float*)&sK[0][0];        // 8192 floats (32 KB)
  float* FV = (float*)&sV[0][0];        // lacc partials
  if (g == 1) {
    for (int mi = 0; mi < 2; ++mi) {
      for (int df = 0; df < 4; ++df)
        for (int r = 0; r < 4; ++r)
          FB[p * 2048 + (mi * 16 + df * 4 + r) * 64 + lane] = o[mi][df][r];
      FV[p * 128 + mi * 64 + lane] = lacc[mi];
    }
  }
  __syncthreads();
  if (g == 0) {
    for (int mi = 0; mi < 2; ++mi) {
      for (int df = 0; df < 4; ++df)
        for (int r = 0; r < 4; ++r)
          o[mi][df][r] += FB[p * 2048 + (mi * 16 + df * 4 + r) * 64 + lane];
      lacc[mi] += FV[p * 128 + mi * 64 + lane];
    }
    // reduce denominators across quads (per q-col m16), normalize, write
    for (int mi = 0; mi < 2; ++mi) {
      lacc[mi] += __shfl_xor(lacc[mi], 16);
      lacc[mi] += __shfl_xor(lacc[mi], 32);
      lacc[mi] = 1.0f / lacc[mi];
    }
    for (int mi = 0; mi < 2; ++mi) {
      float l0 = __shfl(lacc[mi], quad * 4 + 0);
      float l1 = __shfl(lacc[mi], quad * 4 + 1);
      float l2 = __shfl(lacc[mi], quad * 4 + 2);
      float l3 = __shfl(lacc[mi], quad * 4 + 3);
      int qg = qt * 128 + p * 32 + mi * 16 + quad * 4;
      for (int df = 0; df < 4; ++df) {
        int col = h * HDIM + df * 16 + m16;
        size_t base = (size_t)(b * SEQ + qg) * CH + col;
        ao[base + 0 * CH] = f2bf(o[mi][df][0] * l0);
        ao[base + 1 * CH] = f2bf(o[mi][df][1] * l1);
        ao[base + 2 * CH] = f2bf(o[mi][df][2] * l2);
        ao[base + 3 * CH] = f2bf(o[mi][df][3] * l3);
      }
    }
  }
}

// ---------------------------------------------------------------------------
extern "C" void kernel_launch(void* const* d_in, const int* in_sizes, int n_in,
                              void* d_out, int out_size, void* d_ws, size_t ws_size,
                              hipStream_t stream) {
  const float* x    = (const float*)d_in[0];
  const float* gsc  = (const float*)d_in[1];
  const float* gbs  = (const float*)d_in[2];
  const float* wqkv = (const float*)d_in[3];
  const float* bqkv = (const float*)d_in[4];
  const float* wout = (const float*)d_in[5];
  const float* bout = (const float*)d_in[6];
  float* out = (float*)d_out;

  char* ws = (char*)d_ws;
  unsigned short* xn    = (unsigned short*)(ws);                 // 8 MB (8192x512)
  unsigned short* wqkvt = (unsigned short*)(ws + 8388608);       // 1.5 MB (1536x512)
  unsigned short* woutt = (unsigned short*)(ws + 9961472);       // 0.5 MB (512x512)
  unsigned short* qb    = (unsigned short*)(ws + 10485760);      // 8 MB (64,1024,64)
  unsigned short* kb    = (unsigned short*)(ws + 18874368);      // 8 MB (64,1024,64)
  unsigned short* vtb   = (unsigned short*)(ws + 27262976);      // 8 MB (64,64,1024)
  unsigned short* ao    = (unsigned short*)(ws + 35651584);      // 8 MB (8192x512)

  prep_kernel<<<1280, 256, 0, stream>>>(wqkv, wout, x, gsc, gbs, wqkvt, woutt, xn);
  gemm_bt_kernel<0, 128><<<dim3(12, 64), 256, 0, stream>>>(
      xn, wqkvt, 512, 1536, bqkv, nullptr, nullptr, qb, kb, vtb);
  attn_kernel<<<dim3(8, 64), 512, 0, stream>>>(qb, kb, vtb, ao);
  gemm_bt_kernel<1, 64><<<dim3(4, 128), 256, 0, stream>>>(
      ao, woutt, 512, 512, bout, x, out, nullptr, nullptr, nullptr);
}

// Round 8
// 154.162 us; speedup vs baseline: 1.1252x; 1.1188x over previous
//
#include <hip/hip_runtime.h>
#include <hip/hip_bf16.h>

// B=8, H=W=32 (seq=1024), C=512, heads=8, head_dim=64, groups=32
#define SEQ   1024
#define CH    512
#define NHEAD 8
#define HDIM  64
#define BATCH 8

using short8  = __attribute__((ext_vector_type(8))) short;
using short4v = __attribute__((ext_vector_type(4))) short;
using floatx4 = __attribute__((ext_vector_type(4))) float;

__device__ inline unsigned short f2bf(float f) {
  __hip_bfloat16 h = __float2bfloat16(f);
  return __builtin_bit_cast(unsigned short, h);
}

// async 16B global->LDS DMA (lane-linear LDS dest required)
__device__ inline void load_lds16(const void* g, void* l) {
  __builtin_amdgcn_global_load_lds(
      (const __attribute__((address_space(1))) unsigned int*)g,
      (__attribute__((address_space(3))) unsigned int*)l, 16, 0, 0);
}

// ---------------------------------------------------------------------------
// K1: fused prep. blocks 0..255: groupnorm (longest pole -> dispatched first);
// 256..1023: wqkv transpose->bf16; 1024..1279: wout transpose.
// ---------------------------------------------------------------------------
__global__ __launch_bounds__(256) void prep_kernel(
    const float* __restrict__ wqkv, const float* __restrict__ wout,
    const float* __restrict__ x, const float* __restrict__ gsc,
    const float* __restrict__ gbs,
    unsigned short* __restrict__ wqkvt, unsigned short* __restrict__ woutt,
    unsigned short* __restrict__ xn) {
  __shared__ float SH[32 * 33 + 8];
  const int blk = blockIdx.x, tid = threadIdx.x;

  if (blk >= 256) {
    const float* src; unsigned short* dst; int C, bx, by;
    if (blk < 1024) { int t = blk - 256; src = wqkv; dst = wqkvt; C = 1536; bx = t % 48; by = t / 48; }
    else { int t = blk - 1024; src = wout; dst = woutt; C = 512; bx = t & 15; by = t >> 4; }
    float (*T)[33] = (float(*)[33])SH;
    int tx = tid & 31, ty = tid >> 5;
    for (int j = 0; j < 4; ++j)
      T[ty + j * 8][tx] = src[(size_t)(by * 32 + ty + j * 8) * C + bx * 32 + tx];
    __syncthreads();
    for (int j = 0; j < 4; ++j)
      dst[(size_t)(bx * 32 + ty + j * 8) * 512 + by * 32 + tx] = f2bf(T[tx][ty + j * 8]);
    return;
  }

  int bg = blk;
  int b = bg >> 5, g = bg & 31;
  const size_t base = (size_t)b * SEQ * CH + g * 16;

  // single read: 16 float4 per thread held in registers
  float4 v[16];
  float s = 0.f, sq = 0.f;
  for (int i = 0; i < 16; ++i) {
    int c = i * 256 + tid;
    int r = c >> 2, c4 = (c & 3) * 4;
    v[i] = *(const float4*)(x + base + (size_t)r * CH + c4);
    s  += v[i].x + v[i].y + v[i].z + v[i].w;
    sq += v[i].x * v[i].x + v[i].y * v[i].y + v[i].z * v[i].z + v[i].w * v[i].w;
  }
  for (int off = 1; off < 64; off <<= 1) {
    s  += __shfl_xor(s, off);
    sq += __shfl_xor(sq, off);
  }
  float* ls = SH + 1056;
  float* lq = SH + 1060;
  int wid = tid >> 6, lane = tid & 63;
  if (lane == 0) { ls[wid] = s; lq[wid] = sq; }
  __syncthreads();
  float ts = ls[0] + ls[1] + ls[2] + ls[3];
  float tq = lq[0] + lq[1] + lq[2] + lq[3];
  const float inv_n = 1.0f / 16384.0f;
  float mean = ts * inv_n;
  float var  = tq * inv_n - mean * mean;
  float rstd = rsqrtf(var + 1e-6f);

  int c4 = (tid & 3) * 4;
  float4 sc = *(const float4*)(gsc + g * 16 + c4);
  float4 bs = *(const float4*)(gbs + g * 16 + c4);
  for (int i = 0; i < 16; ++i) {
    int c = i * 256 + tid;
    int r = c >> 2;
    ushort4 o;
    o.x = f2bf((v[i].x - mean) * rstd * sc.x + bs.x);
    o.y = f2bf((v[i].y - mean) * rstd * sc.y + bs.y);
    o.z = f2bf((v[i].z - mean) * rstd * sc.z + bs.z);
    o.w = f2bf((v[i].w - mean) * rstd * sc.w + bs.w);
    *(ushort4*)(xn + (size_t)(b * SEQ + r) * CH + g * 16 + c4) = o;
  }
}

// ---------------------------------------------------------------------------
// K2/K4: GEMM C = A(MxK) * Bt(NxK)^T, bf16 in, fp32 acc, MTILE x 128 tile.
// BK=64, global_load_lds staging, XOR-swizzled LDS. Epilogues via LDS ->
// 16B global stores.
// EPI 0 (MTILE=128, QKV): +bias; q scaled (1/64)*log2e; q/k -> (h,s,d);
//     v -> transposed vt (h,d,s) with s PERMUTED within 32-blocks
//     (s=16t+4a+r -> slot 8a+4t+r) so attn PV P-frags form 16x16x32
//     A-operands with zero cross-lane ops.
// EPI 1 (MTILE=64, out):  +bias +residual, fp32 out.
// ---------------------------------------------------------------------------
template <int EPI, int MTILE>
__global__ __launch_bounds__(256) void gemm_bt_kernel(
    const unsigned short* __restrict__ A, const unsigned short* __restrict__ Bt,
    int K, int N,
    const float* __restrict__ bias, const float* __restrict__ resid,
    float* __restrict__ outf,
    unsigned short* __restrict__ qb, unsigned short* __restrict__ kb,
    unsigned short* __restrict__ vtb) {
  constexpr int SMSZ = (MTILE == 128) ? 17408 : 16896;
  constexpr int NI   = (MTILE == 128) ? 4 : 2;
  __shared__ alignas(16) unsigned short SM[SMSZ];
  unsigned short* LA = SM;                 // MTILE x 64, swizzled
  unsigned short* LB = SM + MTILE * 64;    // 128 x 64, swizzled

  const int tid = threadIdx.x;
  const int wid = tid >> 6, lane = tid & 63;
  const int quad = lane >> 4, m16 = lane & 15;
  const int sw = m16 & 7;
  const int wm = (MTILE == 128) ? (wid & 1) * 64 : 0;
  const int wn = (MTILE == 128) ? (wid >> 1) * 64 : wid * 32;
  const int m0 = blockIdx.y * MTILE, n0 = blockIdx.x * 128;

  floatx4 acc[4][NI];
  for (int i = 0; i < 4; ++i)
    for (int j = 0; j < NI; ++j) acc[i][j] = 0.f;

  for (int k0 = 0; k0 < K; k0 += 64) {
    for (int i = 0; i < MTILE / 32; ++i) {
      int c = i * 256 + tid;
      int r = c >> 3, kc = c & 7;
      load_lds16(A + (size_t)(m0 + r) * K + k0 + ((kc ^ (r & 7)) << 3), &LA[c << 3]);
    }
    for (int i = 0; i < 4; ++i) {
      int c = i * 256 + tid;
      int r = c >> 3, kc = c & 7;
      load_lds16(Bt + (size_t)(n0 + r) * K + k0 + ((kc ^ (r & 7)) << 3), &LB[c << 3]);
    }
    __syncthreads();
    for (int kq = 0; kq < 2; ++kq) {
      int csw = (((kq << 2) + quad) ^ sw) << 3;
      short8 af[4], bf[NI];
      for (int mi = 0; mi < 4; ++mi)
        af[mi] = *(const short8*)&LA[(wm + mi * 16 + m16) * 64 + csw];
      for (int ni = 0; ni < NI; ++ni)
        bf[ni] = *(const short8*)&LB[(wn + ni * 16 + m16) * 64 + csw];
      for (int mi = 0; mi < 4; ++mi)
        for (int ni = 0; ni < NI; ++ni)
          acc[mi][ni] = __builtin_amdgcn_mfma_f32_16x16x32_bf16(af[mi], bf[ni], acc[mi][ni], 0, 0, 0);
    }
    __syncthreads();
  }

  // C/D layout: row = quad*4+reg, col = lane&15
  const int b = m0 >> 10;
  if (EPI == 0) {
    const int part = blockIdx.x >> 2;        // 0=q 1=k 2=v (block-uniform)
    if (part < 2) {
      const float qscale = (part == 0) ? 0.0225421381f : 1.0f;  // (1/64)*log2e
      unsigned short* dst = (part == 0) ? qb : kb;
      for (int mi = 0; mi < 4; ++mi)
        for (int ni = 0; ni < 4; ++ni) {
          int ln = wn + ni * 16 + m16;
          float bb = bias[n0 + ln];
          for (int reg = 0; reg < 4; ++reg)
            SM[(wm + mi * 16 + quad * 4 + reg) * 136 + ln] =
                f2bf((acc[mi][ni][reg] + bb) * qscale);
        }
      __syncthreads();
      const int colb = n0 & 511;
      for (int j = 0; j < 8; ++j) {
        int c = j * 256 + tid;               // 2048 16B chunks
        int m = c >> 4, n8 = (c & 15) * 8;
        int h = (colb + n8) >> 6, d = n8 & 63;
        int sp = (m0 & 1023) + m;
        int4 v = *(const int4*)&SM[m * 136 + n8];
        *(int4*)(dst + (((size_t)(b * NHEAD + h)) * SEQ + sp) * HDIM + d) = v;
      }
    } else {
      // v: transpose [n][m] with m permuted within 32-blocks:
      // m = 32u + 16t + 16*... decomposed via mblk = m/16: slot = 32*(mblk>>1)
      // + 8*quad + 4*(mblk&1) + reg
      for (int mi = 0; mi < 4; ++mi)
        for (int ni = 0; ni < 4; ++ni) {
          int ln = wn + ni * 16 + m16;
          float bb = bias[n0 + ln];
          int mblk = (wm >> 4) + mi;
          int sbase = 32 * (mblk >> 1) + 8 * quad + 4 * (mblk & 1);
          for (int reg = 0; reg < 4; ++reg)
            SM[ln * 136 + sbase + reg] = f2bf(acc[mi][ni][reg] + bb);
        }
      __syncthreads();
      int hbase = (n0 - 1024) >> 6;
      for (int j = 0; j < 8; ++j) {
        int c = j * 256 + tid;
        int ld = c >> 4, sp8 = (c & 15) * 8;
        int h = hbase + (ld >> 6), d = ld & 63;
        int4 v = *(const int4*)&SM[ld * 136 + sp8];
        *(int4*)(vtb + ((size_t)(b * NHEAD + h) * HDIM + d) * SEQ + (m0 & 1023) + sp8) = v;
      }
    }
  } else {
    float* SMf = (float*)SM;                 // 64 x 132 fp32
    for (int mi = 0; mi < 4; ++mi)
      for (int ni = 0; ni < NI; ++ni) {
        int ln = wn + ni * 16 + m16;
        float bb = bias[n0 + ln];
        for (int reg = 0; reg < 4; ++reg)
          SMf[(mi * 16 + quad * 4 + reg) * 132 + ln] = acc[mi][ni][reg] + bb;
      }
    __syncthreads();
    for (int j = 0; j < 8; ++j) {
      int c = j * 256 + tid;                 // 2048 float4 chunks
      int m = c >> 5, n4 = (c & 31) * 4;
      size_t idx = (size_t)(m0 + m) * N + n0 + n4;
      float4 v = *(const float4*)&SMf[m * 132 + n4];
      float4 rr = *(const float4*)&resid[idx];
      v.x += rr.x; v.y += rr.y; v.z += rr.z; v.w += rr.w;
      *(float4*)&outf[idx] = v;
    }
  }
}

// ---------------------------------------------------------------------------
// K3: flash attention — r5's proven shape (512 thr, 8 waves x 16 q-rows,
// single 32KB buffer, max-free exp2 softmax) + K=32 PV via the permuted Vt
// layout: P-fragment pairs concatenate into 16x16x32 A-operands (zero
// shuffles), V B-frags are b128 reads.  PV: 16 MFMA + 16 b128 (was 32+32).
// ---------------------------------------------------------------------------
__global__ __launch_bounds__(512) void attn_kernel(
    const unsigned short* __restrict__ qb, const unsigned short* __restrict__ kb,
    const unsigned short* __restrict__ vtb, unsigned short* __restrict__ ao) {
  const int qt = blockIdx.x, head = blockIdx.y;
  const int b = head >> 3, h = head & 7;
  const int tid = threadIdx.x;
  const int wid = tid >> 6, lane = tid & 63;
  const int quad = lane >> 4, m16 = lane & 15;
  const int sw = m16 & 7;

  __shared__ alignas(16) unsigned short sK[8192];   // 128x64, swizzled
  __shared__ alignas(16) unsigned short sV[8192];   // Vt 64x128 (s permuted), swizzled

  const unsigned short* kbase = kb  + (size_t)head * SEQ * HDIM;
  const unsigned short* vbase = vtb + (size_t)head * HDIM * SEQ;

  // Q fragments (pre-scaled by (1/64)*log2e upstream)
  const size_t qrow = (size_t)head * SEQ + qt * 128 + wid * 16 + m16;
  short8 aq0 = *(const short8*)(qb + qrow * HDIM + quad * 8);
  short8 aq1 = *(const short8*)(qb + qrow * HDIM + 32 + quad * 8);

  float lacc = 0.f;
  floatx4 o[4];
  for (int df = 0; df < 4; ++df) o[df] = 0.f;

  for (int kt = 0; kt < 8; ++kt) {
    // stage K tile (128x64) and Vt tile (64x128, permuted s)
    for (int i = 0; i < 2; ++i) {
      int c = i * 512 + tid;
      int r = c >> 3, kc = c & 7;
      load_lds16(kbase + (kt * 128 + r) * HDIM + ((kc ^ (r & 7)) << 3), &sK[c << 3]);
    }
    for (int i = 0; i < 2; ++i) {
      int c = i * 512 + tid;
      int d = c >> 4, kc = c & 15;
      load_lds16(vbase + d * SEQ + kt * 128 + ((kc ^ (d & 7)) << 3), &sV[c << 3]);
    }
    __syncthreads();

    // St = K*Q^T; exp2 + pack immediately. Tile sf=2u+t covers s=u*32+16t+
    // quad*4+r -> A-operand k = quad*8 + 4t + r of pf32[u].
    short8 pf32[4];
    for (int sf = 0; sf < 8; ++sf) {
      const int rb = (sf * 16 + m16) * 64;
      short8 k0 = *(const short8*)&sK[rb + ((quad ^ sw) << 3)];
      short8 k1 = *(const short8*)&sK[rb + (((4 + quad) ^ sw) << 3)];
      floatx4 s = 0.f;
      s = __builtin_amdgcn_mfma_f32_16x16x32_bf16(k0, aq0, s, 0, 0, 0);
      s = __builtin_amdgcn_mfma_f32_16x16x32_bf16(k1, aq1, s, 0, 0, 0);
      const int u = sf >> 1, t4 = (sf & 1) * 4;
      for (int r = 0; r < 4; ++r) {
        float p = exp2f(s[r]);
        lacc += p;
        pf32[u][t4 + r] = (short)f2bf(p);
      }
    }

    // O += P*V  (K=32: B-frag = 8 consecutive permuted slots, b128)
    for (int u = 0; u < 4; ++u) {
      const int chunk = ((u * 4 + quad) ^ sw) << 3;
      for (int df = 0; df < 4; ++df) {
        short8 bv = *(const short8*)&sV[(df * 16 + m16) * 128 + chunk];
        o[df] = __builtin_amdgcn_mfma_f32_16x16x32_bf16(pf32[u], bv, o[df], 0, 0, 0);
      }
    }
    __syncthreads();
  }

  // reduce denominator across quads (per q-col m16), normalize, write
  lacc += __shfl_xor(lacc, 16);
  lacc += __shfl_xor(lacc, 32);
  lacc = 1.0f / lacc;
  float l0 = __shfl(lacc, quad * 4 + 0);
  float l1 = __shfl(lacc, quad * 4 + 1);
  float l2 = __shfl(lacc, quad * 4 + 2);
  float l3 = __shfl(lacc, quad * 4 + 3);
  int qg = qt * 128 + wid * 16 + quad * 4;
  for (int df = 0; df < 4; ++df) {
    int col = h * HDIM + df * 16 + m16;
    size_t base = (size_t)(b * SEQ + qg) * CH + col;
    ao[base + 0 * CH] = f2bf(o[df][0] * l0);
    ao[base + 1 * CH] = f2bf(o[df][1] * l1);
    ao[base + 2 * CH] = f2bf(o[df][2] * l2);
    ao[base + 3 * CH] = f2bf(o[df][3] * l3);
  }
}

// ---------------------------------------------------------------------------
extern "C" void kernel_launch(void* const* d_in, const int* in_sizes, int n_in,
                              void* d_out, int out_size, void* d_ws, size_t ws_size,
                              hipStream_t stream) {
  const float* x    = (const float*)d_in[0];
  const float* gsc  = (const float*)d_in[1];
  const float* gbs  = (const float*)d_in[2];
  const float* wqkv = (const float*)d_in[3];
  const float* bqkv = (const float*)d_in[4];
  const float* wout = (const float*)d_in[5];
  const float* bout = (const float*)d_in[6];
  float* out = (float*)d_out;

  char* ws = (char*)d_ws;
  unsigned short* xn    = (unsigned short*)(ws);                 // 8 MB (8192x512)
  unsigned short* wqkvt = (unsigned short*)(ws + 8388608);       // 1.5 MB (1536x512)
  unsigned short* woutt = (unsigned short*)(ws + 9961472);       // 0.5 MB (512x512)
  unsigned short* qb    = (unsigned short*)(ws + 10485760);      // 8 MB (64,1024,64)
  unsigned short* kb    = (unsigned short*)(ws + 18874368);      // 8 MB (64,1024,64)
  unsigned short* vtb   = (unsigned short*)(ws + 27262976);      // 8 MB (64,64,1024)
  unsigned short* ao    = (unsigned short*)(ws + 35651584);      // 8 MB (8192x512)

  prep_kernel<<<1280, 256, 0, stream>>>(wqkv, wout, x, gsc, gbs, wqkvt, woutt, xn);
  gemm_bt_kernel<0, 128><<<dim3(12, 64), 256, 0, stream>>>(
      xn, wqkvt, 512, 1536, bqkv, nullptr, nullptr, qb, kb, vtb);
  attn_kernel<<<dim3(8, 64), 512, 0, stream>>>(qb, kb, vtb, ao);
  gemm_bt_kernel<1, 64><<<dim3(4, 128), 256, 0, stream>>>(
      ao, woutt, 512, 512, bout, x, out, nullptr, nullptr, nullptr);
}

// Round 9
// 150.154 us; speedup vs baseline: 1.1552x; 1.0267x over previous
//
#include <hip/hip_runtime.h>
#include <hip/hip_bf16.h>

// B=8, H=W=32 (seq=1024), C=512, heads=8, head_dim=64, groups=32
#define SEQ   1024
#define CH    512
#define NHEAD 8
#define HDIM  64
#define BATCH 8

using short8  = __attribute__((ext_vector_type(8))) short;
using short4v = __attribute__((ext_vector_type(4))) short;
using floatx4 = __attribute__((ext_vector_type(4))) float;

__device__ inline unsigned short f2bf(float f) {
  __hip_bfloat16 h = __float2bfloat16(f);
  return __builtin_bit_cast(unsigned short, h);
}

// async 16B global->LDS DMA (lane-linear LDS dest required)
__device__ inline void load_lds16(const void* g, void* l) {
  __builtin_amdgcn_global_load_lds(
      (const __attribute__((address_space(1))) unsigned int*)g,
      (__attribute__((address_space(3))) unsigned int*)l, 16, 0, 0);
}

// ---------------------------------------------------------------------------
// K1a: GN partial stats (blocks 0..2047: (bg,chunk) of 128 rows x 16 ch) +
// weight transposes (2048..2815 wqkv, 2816..3071 wout).  Partials go to ws —
// no atomics, no zero-init needed.
// ---------------------------------------------------------------------------
__global__ __launch_bounds__(256) void prep_stats_kernel(
    const float* __restrict__ wqkv, const float* __restrict__ wout,
    const float* __restrict__ x,
    unsigned short* __restrict__ wqkvt, unsigned short* __restrict__ woutt,
    float2* __restrict__ stats) {
  __shared__ float SH[32 * 33 + 8];
  const int blk = blockIdx.x, tid = threadIdx.x;

  if (blk >= 2048) {
    const float* src; unsigned short* dst; int C, bx, by;
    if (blk < 2816) { int t = blk - 2048; src = wqkv; dst = wqkvt; C = 1536; bx = t % 48; by = t / 48; }
    else { int t = blk - 2816; src = wout; dst = woutt; C = 512; bx = t & 15; by = t >> 4; }
    float (*T)[33] = (float(*)[33])SH;
    int tx = tid & 31, ty = tid >> 5;
    for (int j = 0; j < 4; ++j)
      T[ty + j * 8][tx] = src[(size_t)(by * 32 + ty + j * 8) * C + bx * 32 + tx];
    __syncthreads();
    for (int j = 0; j < 4; ++j)
      dst[(size_t)(bx * 32 + ty + j * 8) * 512 + by * 32 + tx] = f2bf(T[tx][ty + j * 8]);
    return;
  }

  const int bg = blk >> 3, chunk = blk & 7;
  const int b = bg >> 5, g = bg & 31;
  const size_t base = (size_t)b * SEQ * CH + (size_t)chunk * 128 * CH + g * 16;

  float s = 0.f, sq = 0.f;
  for (int i = 0; i < 2; ++i) {
    int c = i * 256 + tid;                      // 512 float4 chunks
    int r = c >> 2, c4 = (c & 3) * 4;
    float4 v = *(const float4*)(x + base + (size_t)r * CH + c4);
    s  += v.x + v.y + v.z + v.w;
    sq += v.x * v.x + v.y * v.y + v.z * v.z + v.w * v.w;
  }
  for (int off = 1; off < 64; off <<= 1) {
    s  += __shfl_xor(s, off);
    sq += __shfl_xor(sq, off);
  }
  float* ls = SH + 1056;
  float* lq = SH + 1060;
  int wid = tid >> 6, lane = tid & 63;
  if (lane == 0) { ls[wid] = s; lq[wid] = sq; }
  __syncthreads();
  if (tid == 0) {
    float2 p;
    p.x = ls[0] + ls[1] + ls[2] + ls[3];
    p.y = lq[0] + lq[1] + lq[2] + lq[3];
    stats[(bg << 3) + chunk] = p;
  }
}

// ---------------------------------------------------------------------------
// K1b: GN apply.  2048 blocks (bg,chunk); reads 8 partials, normalizes
// 128 rows x 16 ch, writes bf16 xn.  Fully parallel (8 blocks/CU).
// ---------------------------------------------------------------------------
__global__ __launch_bounds__(256) void prep_apply_kernel(
    const float* __restrict__ x, const float* __restrict__ gsc,
    const float* __restrict__ gbs, const float2* __restrict__ stats,
    unsigned short* __restrict__ xn) {
  const int blk = blockIdx.x, tid = threadIdx.x;
  const int bg = blk >> 3, chunk = blk & 7;
  const int b = bg >> 5, g = bg & 31;

  float ts = 0.f, tq = 0.f;
  for (int i = 0; i < 8; ++i) {
    float2 p = stats[(bg << 3) + i];
    ts += p.x; tq += p.y;
  }
  const float inv_n = 1.0f / 16384.0f;
  float mean = ts * inv_n;
  float var  = tq * inv_n - mean * mean;
  float rstd = rsqrtf(var + 1e-6f);

  const size_t base = (size_t)b * SEQ * CH + (size_t)chunk * 128 * CH + g * 16;
  const size_t obase = (size_t)(b * SEQ + chunk * 128) * CH + g * 16;
  int c4 = (tid & 3) * 4;
  float4 sc = *(const float4*)(gsc + g * 16 + c4);
  float4 bs = *(const float4*)(gbs + g * 16 + c4);
  for (int i = 0; i < 2; ++i) {
    int c = i * 256 + tid;
    int r = c >> 2;
    float4 v = *(const float4*)(x + base + (size_t)r * CH + c4);
    ushort4 o;
    o.x = f2bf((v.x - mean) * rstd * sc.x + bs.x);
    o.y = f2bf((v.y - mean) * rstd * sc.y + bs.y);
    o.z = f2bf((v.z - mean) * rstd * sc.z + bs.z);
    o.w = f2bf((v.w - mean) * rstd * sc.w + bs.w);
    *(ushort4*)(xn + obase + (size_t)r * CH + c4) = o;
  }
}

// ---------------------------------------------------------------------------
// K2/K4: GEMM C = A(MxK) * Bt(NxK)^T, bf16 in, fp32 acc, MTILE x 128 tile.
// Grid is (m-tile, n-tile) so blocks sharing an A-tile get the same
// linear%8 -> same XCD (L2 locality).  BK=64, global_load_lds staging,
// XOR-swizzled LDS.  Epilogues via LDS -> 16B global stores.
// EPI 0 (MTILE=128, QKV): +bias; q scaled (1/64)*log2e; q/k -> (h,s,d);
//     v -> transposed vt (h,d,s) with s permuted within 32-blocks so attn
//     PV P-frags form 16x16x32 A-operands with zero cross-lane ops.
// EPI 1 (MTILE=64, out):  +bias +residual, fp32 out.
// ---------------------------------------------------------------------------
template <int EPI, int MTILE>
__global__ __launch_bounds__(256) void gemm_bt_kernel(
    const unsigned short* __restrict__ A, const unsigned short* __restrict__ Bt,
    int K, int N,
    const float* __restrict__ bias, const float* __restrict__ resid,
    float* __restrict__ outf,
    unsigned short* __restrict__ qb, unsigned short* __restrict__ kb,
    unsigned short* __restrict__ vtb) {
  constexpr int SMSZ = (MTILE == 128) ? 17408 : 16896;
  constexpr int NI   = (MTILE == 128) ? 4 : 2;
  __shared__ alignas(16) unsigned short SM[SMSZ];
  unsigned short* LA = SM;                 // MTILE x 64, swizzled
  unsigned short* LB = SM + MTILE * 64;    // 128 x 64, swizzled

  const int tid = threadIdx.x;
  const int wid = tid >> 6, lane = tid & 63;
  const int quad = lane >> 4, m16 = lane & 15;
  const int sw = m16 & 7;
  const int wm = (MTILE == 128) ? (wid & 1) * 64 : 0;
  const int wn = (MTILE == 128) ? (wid >> 1) * 64 : wid * 32;
  const int m0 = blockIdx.x * MTILE, n0 = blockIdx.y * 128;

  floatx4 acc[4][NI];
  for (int i = 0; i < 4; ++i)
    for (int j = 0; j < NI; ++j) acc[i][j] = 0.f;

  for (int k0 = 0; k0 < K; k0 += 64) {
    for (int i = 0; i < MTILE / 32; ++i) {
      int c = i * 256 + tid;
      int r = c >> 3, kc = c & 7;
      load_lds16(A + (size_t)(m0 + r) * K + k0 + ((kc ^ (r & 7)) << 3), &LA[c << 3]);
    }
    for (int i = 0; i < 4; ++i) {
      int c = i * 256 + tid;
      int r = c >> 3, kc = c & 7;
      load_lds16(Bt + (size_t)(n0 + r) * K + k0 + ((kc ^ (r & 7)) << 3), &LB[c << 3]);
    }
    __syncthreads();
    for (int kq = 0; kq < 2; ++kq) {
      int csw = (((kq << 2) + quad) ^ sw) << 3;
      short8 af[4], bf[NI];
      for (int mi = 0; mi < 4; ++mi)
        af[mi] = *(const short8*)&LA[(wm + mi * 16 + m16) * 64 + csw];
      for (int ni = 0; ni < NI; ++ni)
        bf[ni] = *(const short8*)&LB[(wn + ni * 16 + m16) * 64 + csw];
      for (int mi = 0; mi < 4; ++mi)
        for (int ni = 0; ni < NI; ++ni)
          acc[mi][ni] = __builtin_amdgcn_mfma_f32_16x16x32_bf16(af[mi], bf[ni], acc[mi][ni], 0, 0, 0);
    }
    __syncthreads();
  }

  // C/D layout: row = quad*4+reg, col = lane&15
  const int b = m0 >> 10;
  if (EPI == 0) {
    const int part = n0 >> 9;                // 0=q 1=k 2=v (block-uniform)
    if (part < 2) {
      const float qscale = (part == 0) ? 0.0225421381f : 1.0f;  // (1/64)*log2e
      unsigned short* dst = (part == 0) ? qb : kb;
      for (int mi = 0; mi < 4; ++mi)
        for (int ni = 0; ni < 4; ++ni) {
          int ln = wn + ni * 16 + m16;
          float bb = bias[n0 + ln];
          for (int reg = 0; reg < 4; ++reg)
            SM[(wm + mi * 16 + quad * 4 + reg) * 136 + ln] =
                f2bf((acc[mi][ni][reg] + bb) * qscale);
        }
      __syncthreads();
      const int colb = n0 & 511;
      for (int j = 0; j < 8; ++j) {
        int c = j * 256 + tid;               // 2048 16B chunks
        int m = c >> 4, n8 = (c & 15) * 8;
        int h = (colb + n8) >> 6, d = n8 & 63;
        int sp = (m0 & 1023) + m;
        int4 v = *(const int4*)&SM[m * 136 + n8];
        *(int4*)(dst + (((size_t)(b * NHEAD + h)) * SEQ + sp) * HDIM + d) = v;
      }
    } else {
      // v: transpose [n][m], m permuted within 32-blocks (slot = 32*(mblk>>1)
      // + 8*quad + 4*(mblk&1) + reg) for attn's K=32 PV A-operands
      for (int mi = 0; mi < 4; ++mi)
        for (int ni = 0; ni < 4; ++ni) {
          int ln = wn + ni * 16 + m16;
          float bb = bias[n0 + ln];
          int mblk = (wm >> 4) + mi;
          int sbase = 32 * (mblk >> 1) + 8 * quad + 4 * (mblk & 1);
          for (int reg = 0; reg < 4; ++reg)
            SM[ln * 136 + sbase + reg] = f2bf(acc[mi][ni][reg] + bb);
        }
      __syncthreads();
      int hbase = (n0 - 1024) >> 6;
      for (int j = 0; j < 8; ++j) {
        int c = j * 256 + tid;
        int ld = c >> 4, sp8 = (c & 15) * 8;
        int h = hbase + (ld >> 6), d = ld & 63;
        int4 v = *(const int4*)&SM[ld * 136 + sp8];
        *(int4*)(vtb + ((size_t)(b * NHEAD + h) * HDIM + d) * SEQ + (m0 & 1023) + sp8) = v;
      }
    }
  } else {
    float* SMf = (float*)SM;                 // 64 x 132 fp32
    for (int mi = 0; mi < 4; ++mi)
      for (int ni = 0; ni < NI; ++ni) {
        int ln = wn + ni * 16 + m16;
        float bb = bias[n0 + ln];
        for (int reg = 0; reg < 4; ++reg)
          SMf[(mi * 16 + quad * 4 + reg) * 132 + ln] = acc[mi][ni][reg] + bb;
      }
    __syncthreads();
    for (int j = 0; j < 8; ++j) {
      int c = j * 256 + tid;                 // 2048 float4 chunks
      int m = c >> 5, n4 = (c & 31) * 4;
      size_t idx = (size_t)(m0 + m) * N + n0 + n4;
      float4 v = *(const float4*)&SMf[m * 132 + n4];
      float4 rr = *(const float4*)&resid[idx];
      v.x += rr.x; v.y += rr.y; v.z += rr.z; v.w += rr.w;
      *(float4*)&outf[idx] = v;
    }
  }
}

// ---------------------------------------------------------------------------
// K3: flash attention — r8's proven structure (512 thr, 8 waves x 16 q-rows,
// single 32KB buffer, max-free exp2 softmax, K=32 PV via permuted Vt).
// Grid swapped to (head, qt) so the 8 qt-blocks sharing a head's K/V map to
// the same XCD (same linear%8) -> L2 locality, less HBM re-fetch.
// ---------------------------------------------------------------------------
__global__ __launch_bounds__(512) void attn_kernel(
    const unsigned short* __restrict__ qb, const unsigned short* __restrict__ kb,
    const unsigned short* __restrict__ vtb, unsigned short* __restrict__ ao) {
  const int head = blockIdx.x, qt = blockIdx.y;
  const int b = head >> 3, h = head & 7;
  const int tid = threadIdx.x;
  const int wid = tid >> 6, lane = tid & 63;
  const int quad = lane >> 4, m16 = lane & 15;
  const int sw = m16 & 7;

  __shared__ alignas(16) unsigned short sK[8192];   // 128x64, swizzled
  __shared__ alignas(16) unsigned short sV[8192];   // Vt 64x128 (s permuted), swizzled

  const unsigned short* kbase = kb  + (size_t)head * SEQ * HDIM;
  const unsigned short* vbase = vtb + (size_t)head * HDIM * SEQ;

  // Q fragments (pre-scaled by (1/64)*log2e upstream)
  const size_t qrow = (size_t)head * SEQ + qt * 128 + wid * 16 + m16;
  short8 aq0 = *(const short8*)(qb + qrow * HDIM + quad * 8);
  short8 aq1 = *(const short8*)(qb + qrow * HDIM + 32 + quad * 8);

  float lacc = 0.f;
  floatx4 o[4];
  for (int df = 0; df < 4; ++df) o[df] = 0.f;

  for (int kt = 0; kt < 8; ++kt) {
    // stage K tile (128x64) and Vt tile (64x128, permuted s)
    for (int i = 0; i < 2; ++i) {
      int c = i * 512 + tid;
      int r = c >> 3, kc = c & 7;
      load_lds16(kbase + (kt * 128 + r) * HDIM + ((kc ^ (r & 7)) << 3), &sK[c << 3]);
    }
    for (int i = 0; i < 2; ++i) {
      int c = i * 512 + tid;
      int d = c >> 4, kc = c & 15;
      load_lds16(vbase + d * SEQ + kt * 128 + ((kc ^ (d & 7)) << 3), &sV[c << 3]);
    }
    __syncthreads();

    // St = K*Q^T; exp2 + pack immediately. sf=2u+t -> A-operand k=quad*8+4t+r
    short8 pf32[4];
    for (int sf = 0; sf < 8; ++sf) {
      const int rb = (sf * 16 + m16) * 64;
      short8 k0 = *(const short8*)&sK[rb + ((quad ^ sw) << 3)];
      short8 k1 = *(const short8*)&sK[rb + (((4 + quad) ^ sw) << 3)];
      floatx4 s = 0.f;
      s = __builtin_amdgcn_mfma_f32_16x16x32_bf16(k0, aq0, s, 0, 0, 0);
      s = __builtin_amdgcn_mfma_f32_16x16x32_bf16(k1, aq1, s, 0, 0, 0);
      const int u = sf >> 1, t4 = (sf & 1) * 4;
      for (int r = 0; r < 4; ++r) {
        float p = exp2f(s[r]);
        lacc += p;
        pf32[u][t4 + r] = (short)f2bf(p);
      }
    }

    // O += P*V  (K=32: B-frag = 8 consecutive permuted slots, b128)
    for (int u = 0; u < 4; ++u) {
      const int chunk = ((u * 4 + quad) ^ sw) << 3;
      for (int df = 0; df < 4; ++df) {
        short8 bv = *(const short8*)&sV[(df * 16 + m16) * 128 + chunk];
        o[df] = __builtin_amdgcn_mfma_f32_16x16x32_bf16(pf32[u], bv, o[df], 0, 0, 0);
      }
    }
    __syncthreads();
  }

  // reduce denominator across quads (per q-col m16), normalize, write
  lacc += __shfl_xor(lacc, 16);
  lacc += __shfl_xor(lacc, 32);
  lacc = 1.0f / lacc;
  float l0 = __shfl(lacc, quad * 4 + 0);
  float l1 = __shfl(lacc, quad * 4 + 1);
  float l2 = __shfl(lacc, quad * 4 + 2);
  float l3 = __shfl(lacc, quad * 4 + 3);
  int qg = qt * 128 + wid * 16 + quad * 4;
  for (int df = 0; df < 4; ++df) {
    int col = h * HDIM + df * 16 + m16;
    size_t base = (size_t)(b * SEQ + qg) * CH + col;
    ao[base + 0 * CH] = f2bf(o[df][0] * l0);
    ao[base + 1 * CH] = f2bf(o[df][1] * l1);
    ao[base + 2 * CH] = f2bf(o[df][2] * l2);
    ao[base + 3 * CH] = f2bf(o[df][3] * l3);
  }
}

// ---------------------------------------------------------------------------
extern "C" void kernel_launch(void* const* d_in, const int* in_sizes, int n_in,
                              void* d_out, int out_size, void* d_ws, size_t ws_size,
                              hipStream_t stream) {
  const float* x    = (const float*)d_in[0];
  const float* gsc  = (const float*)d_in[1];
  const float* gbs  = (const float*)d_in[2];
  const float* wqkv = (const float*)d_in[3];
  const float* bqkv = (const float*)d_in[4];
  const float* wout = (const float*)d_in[5];
  const float* bout = (const float*)d_in[6];
  float* out = (float*)d_out;

  char* ws = (char*)d_ws;
  unsigned short* xn    = (unsigned short*)(ws);                 // 8 MB (8192x512)
  unsigned short* wqkvt = (unsigned short*)(ws + 8388608);       // 1.5 MB (1536x512)
  unsigned short* woutt = (unsigned short*)(ws + 9961472);       // 0.5 MB (512x512)
  unsigned short* qb    = (unsigned short*)(ws + 10485760);      // 8 MB (64,1024,64)
  unsigned short* kb    = (unsigned short*)(ws + 18874368);      // 8 MB (64,1024,64)
  unsigned short* vtb   = (unsigned short*)(ws + 27262976);      // 8 MB (64,64,1024)
  unsigned short* ao    = (unsigned short*)(ws + 35651584);      // 8 MB (8192x512)
  float2*         stats = (float2*)(ws + 44040192);              // 16 KB (2048 f2)

  prep_stats_kernel<<<3072, 256, 0, stream>>>(wqkv, wout, x, wqkvt, woutt, stats);
  prep_apply_kernel<<<2048, 256, 0, stream>>>(x, gsc, gbs, stats, xn);
  gemm_bt_kernel<0, 128><<<dim3(64, 12), 256, 0, stream>>>(
      xn, wqkvt, 512, 1536, bqkv, nullptr, nullptr, qb, kb, vtb);
  attn_kernel<<<dim3(64, 8), 512, 0, stream>>>(qb, kb, vtb, ao);
  gemm_bt_kernel<1, 64><<<dim3(128, 4), 256, 0, stream>>>(
      ao, woutt, 512, 512, bout, x, out, nullptr, nullptr, nullptr);
}